// Round 4
// baseline (5163.021 us; speedup 1.0000x reference)
//
#include <hip/hip_runtime.h>

#define DEVI __device__ __forceinline__

typedef __attribute__((ext_vector_type(8)))  short short8;
typedef __attribute__((ext_vector_type(4)))  short short4v;
typedef __attribute__((ext_vector_type(16))) float f32x16;

// ---- problem dims ----
constexpr int NROW = 8192;
constexpr int HD   = 512;
constexpr int DIN  = 256;
constexpr int NC   = 10;

// ---- tiling ----
constexpr int NP  = 22;   // gate/up pair tiles: 682 padded to 704 = 22*32
constexpr int KT1 = 32;   // GEMM1 K = 512 / 16
constexpr int KT2 = 44;   // GEMM2 K = 704 / 16
constexpr int KTX = 16;   // x_proj K = 256 / 16
constexpr int NTH = 16;   // H-wide outputs: 512 / 32

// packed strides (shorts per kt-step)
constexpr int KSTEP1 = NP*64*32;   // GEMM1: [gh8,gl8,uh8,ul8] per lane per (kt,nt)
constexpr int KSTEPD = NTH*64*16;  // GEMM2 / x_proj: [h8,l8]

// packed weight tensor sizes (shorts), padded +4 kt-steps for branch-free ring prefetch
constexpr int SZ_P1  = (KT1+4)*KSTEP1;
constexpr int SZ_PD  = (KT2+4)*KSTEPD;
constexpr int SZ_PIN = (KTX+4)*KSTEPD;

DEVI short f2bf(float x){
  unsigned u = __builtin_bit_cast(unsigned, x);
  unsigned r = u + 0x7FFFu + ((u >> 16) & 1u);
  return (short)(r >> 16);
}
DEVI float bf2f(short s){
  unsigned u = ((unsigned)(unsigned short)s) << 16;
  return __builtin_bit_cast(float, u);
}
DEVI f32x16 MF(short8 a, short8 b, f32x16 c){
  return __builtin_amdgcn_mfma_f32_32x32x16_bf16(a, b, c, 0, 0, 0);
}
DEVI f32x16 fzero(){
  f32x16 v;
  #pragma unroll
  for (int i = 0; i < 16; ++i) v[i] = 0.f;
  return v;
}

// store silu(gate)*up for one 32-col pair into inter frag buffers (hi/lo bf16)
DEVI void silu_store(int p, const f32x16& cg, const f32x16& cu,
                     short* INh_, short* INl_, int l)
{
  const int m = l & 31, g = l >> 5;
  #pragma unroll
  for (int q = 0; q < 4; ++q) {
    short4v hi, lo;
    #pragma unroll
    for (int pos = 0; pos < 4; ++pos) {
      const int r = q*4 + pos;
      float gv = cg[r], uv = cu[r];
      float sv = (gv / (1.0f + __expf(-gv))) * uv;   // silu(g)*u
      short h = f2bf(sv);
      hi[pos] = h;
      lo[pos] = f2bf(sv - bf2f(h));
    }
    const int kt2  = 2*p + (q >> 1);
    const int slot = ((q & 1) << 5) + m;
    const int base = (kt2*64 + slot)*8 + (g << 2);
    *(short4v*)&INh_[base] = hi;
    *(short4v*)&INl_[base] = lo;
  }
}

// GEMM1, ONE (gate,up) pair, depth-4 register ring pipeline (static indices only).
// bW = P + ((pair*64 + l))*32. Requires 4 kt-steps of tail padding in P.
DEVI void g1_pair(const short* __restrict__ bW,
                  const short* __restrict__ A1h_, const short* __restrict__ A1l_,
                  int l, f32x16& ag, f32x16& au)
{
  short8 R0[4], R1[4], R2[4], R3[4];   // ring slots: {gh,gl,uh,ul}
  auto LD = [&](short8* R, int kt) {
    const short* p = bW + (size_t)kt*KSTEP1;
    R[0] = *(const short8*)(p);
    R[1] = *(const short8*)(p + 8);
    R[2] = *(const short8*)(p + 16);
    R[3] = *(const short8*)(p + 24);
  };
  LD(R0, 0); LD(R1, 1); LD(R2, 2); LD(R3, 3);
  #pragma unroll 1
  for (int kt = 0; kt < KT1; kt += 4) {
    #define G1STEP(R, u) { \
      short8 bh = *(const short8*)&A1h_[((kt+u)*64 + l)*8]; \
      short8 bl = *(const short8*)&A1l_[((kt+u)*64 + l)*8]; \
      ag = MF(R[0], bh, ag); ag = MF(R[1], bh, ag); ag = MF(R[0], bl, ag); \
      au = MF(R[2], bh, au); au = MF(R[3], bh, au); au = MF(R[2], bl, au); \
      LD(R, kt + u + 4); }
    G1STEP(R0, 0) G1STEP(R1, 1) G1STEP(R2, 2) G1STEP(R3, 3)
    #undef G1STEP
  }
}

// GEMM2 / x_proj: two output cols, depth-4 register ring pipeline.
// bD = P + ((2w*64 + l))*16. Requires 4 kt-steps of tail padding in P.
template<int KT>
DEVI void g2_run(const short* __restrict__ bD,
                 const short* __restrict__ Bh_, const short* __restrict__ Bl_,
                 int l, f32x16& c0, f32x16& c1)
{
  short8 R0[4], R1[4], R2[4], R3[4];   // ring slots: {d0h,d0l,d1h,d1l}
  auto LD = [&](short8* R, int kt) {
    const short* p = bD + (size_t)kt*KSTEPD;
    R[0] = *(const short8*)(p);
    R[1] = *(const short8*)(p + 8);
    R[2] = *(const short8*)(p + 1024);
    R[3] = *(const short8*)(p + 1032);
  };
  LD(R0, 0); LD(R1, 1); LD(R2, 2); LD(R3, 3);
  #pragma unroll 1
  for (int kt = 0; kt < KT; kt += 4) {
    #define G2STEP(R, u) { \
      short8 bh = *(const short8*)&Bh_[((kt+u)*64 + l)*8]; \
      short8 bl = *(const short8*)&Bl_[((kt+u)*64 + l)*8]; \
      c0 = MF(R[0], bh, c0); c0 = MF(R[1], bh, c0); c0 = MF(R[0], bl, c0); \
      c1 = MF(R[2], bh, c1); c1 = MF(R[3], bh, c1); c1 = MF(R[2], bl, c1); \
      LD(R, kt + u + 4); }
    G2STEP(R0, 0) G2STEP(R1, 1) G2STEP(R2, 2) G2STEP(R3, 3)
    #undef G2STEP
  }
}

// one SwiGLU sublayer + residual + rmsnorm, in-place on register state S[32]
DEVI void sublayer(float (&S)[32], const short* __restrict__ PW, const short* __restrict__ PD,
                   short* A1h_, short* A1l_, short* INh_, short* INl_,
                   float* rmsS_, int w, int l)
{
  const int m = l & 31, g = l >> 5;
  // ---- stage h0 fragments (hi/lo) into LDS ----
  #pragma unroll
  for (int t = 0; t < 2; ++t) {
    #pragma unroll
    for (int q = 0; q < 4; ++q) {
      short4v hi, lo;
      #pragma unroll
      for (int pos = 0; pos < 4; ++pos) {
        float v = S[t*16 + q*4 + pos];
        short h = f2bf(v);
        hi[pos] = h;
        lo[pos] = f2bf(v - bf2f(h));
      }
      const int kt   = 4*w + 2*t + (q >> 1);
      const int slot = ((q & 1) << 5) + m;
      const int base = (kt*64 + slot)*8 + (g << 2);
      *(short4v*)&A1h_[base] = hi;
      *(short4v*)&A1l_[base] = lo;
    }
  }
  __syncthreads();
  // ---- GEMM1 (weights are MFMA A-operand), one pair per pass ----
  {
    f32x16 ag = fzero(), au = fzero();
    g1_pair(PW + ((size_t)(w*64 + l))*32, A1h_, A1l_, l, ag, au);
    silu_store(w, ag, au, INh_, INl_, l);
  }
  {
    f32x16 ag = fzero(), au = fzero();
    g1_pair(PW + ((size_t)((w + 8)*64 + l))*32, A1h_, A1l_, l, ag, au);
    silu_store(w + 8, ag, au, INh_, INl_, l);
  }
  if (w < 6) {
    f32x16 ag = fzero(), au = fzero();
    g1_pair(PW + ((size_t)((w + 16)*64 + l))*32, A1h_, A1l_, l, ag, au);
    silu_store(w + 16, ag, au, INh_, INl_, l);
  }
  __syncthreads();
  // ---- GEMM2 ----
  f32x16 c0 = fzero(), c1 = fzero();
  g2_run<KT2>(PD + ((size_t)(2*w*64 + l))*16, INh_, INl_, l, c0, c1);
  // ---- residual + rmsnorm (thread-local: C^T frags align with state) ----
  float ss = 0.f;
  #pragma unroll
  for (int s = 0; s < 32; ++s) {
    float y = S[s] + (s < 16 ? c0[s & 15] : c1[s & 15]);
    S[s] = y;
    ss += y*y;
  }
  ss += __shfl_xor(ss, 32);
  if (l < 32) rmsS_[w*32 + l] = ss;
  __syncthreads();
  float tot = 0.f;
  #pragma unroll
  for (int wv = 0; wv < 8; ++wv) tot += rmsS_[wv*32 + m];
  const float rinv = 1.0f / sqrtf(tot * (1.0f/512.0f) + 1e-6f);
  #pragma unroll
  for (int s = 0; s < 32; ++s) S[s] *= rinv;
}

__global__ __launch_bounds__(512, 2) void trm_main(
    const float* __restrict__ x,
    const float* __restrict__ b_in,
    const float* __restrict__ W_fb,
    const float* __restrict__ b_fb,
    const float* __restrict__ H_init,
    const float* __restrict__ L_init,
    const float* __restrict__ W_out,
    const float* __restrict__ b_out,
    float* __restrict__ xp,
    const short* __restrict__ PIN,
    const short* __restrict__ P1, const short* __restrict__ PD1,
    const short* __restrict__ P2, const short* __restrict__ PD2,
    float* __restrict__ out)
{
  __shared__ alignas(16) char smem[156672];
  short* A1h  = (short*)(smem);            // [32][64][8] bf16-hi h0 frags (32KB)
  short* A1l  = (short*)(smem + 32768);    // lo (32KB)
  short* INh  = (short*)(smem + 65536);    // [44][64][8] inter hi (45KB)
  short* INl  = (short*)(smem + 110592);   // lo (45KB)
  float* rmsS = (float*)(smem + 155648);   // [8][32]
  float* lgS  = (float*)(smem);            // k-epilogue alias over A1 region
  float* pbS  = (float*)(smem + 10240);

  const int tid = threadIdx.x;
  const int l = tid & 63;
  const int w = tid >> 6;
  const int m = l & 31;
  const int g = l >> 5;
  const int wg = blockIdx.x;
  const int row0 = wg * 32;

  float zL[32], zH[32], cb[32];

  // ================= x_proj = x @ W_in + b_in =================
  #pragma unroll
  for (int kk = 0; kk < 2; ++kk) {
    const int kt = 2*w + kk;
    const float4* xr = (const float4*)(x + (size_t)(row0 + m)*DIN + kt*16 + g*8);
    float4 v0 = xr[0];
    float4 v1 = xr[1];
    float v[8] = {v0.x, v0.y, v0.z, v0.w, v1.x, v1.y, v1.z, v1.w};
    short8 hi, lo;
    #pragma unroll
    for (int i = 0; i < 8; ++i) {
      short h = f2bf(v[i]);
      hi[i] = h;
      lo[i] = f2bf(v[i] - bf2f(h));
    }
    const int base = (kt*64 + l)*8;
    *(short8*)&A1h[base] = hi;
    *(short8*)&A1l[base] = lo;
  }
  __syncthreads();
  {
    f32x16 c0 = fzero(), c1 = fzero();
    g2_run<KTX>(PIN + ((size_t)(2*w*64 + l))*16, A1h, A1l, l, c0, c1);
    #pragma unroll
    for (int s = 0; s < 32; ++s) {
      const int r = s & 15;
      const int cc = w*64 + (s >> 4)*32 + (r & 3) + ((r >> 2) << 3) + (g << 2);
      float v = (s < 16 ? c0[r] : c1[r]) + b_in[cc];
      cb[s] = v;
      xp[(size_t)(wg*8 + w)*2048 + s*64 + l] = v;
      zH[s] = H_init[cc];
      zL[s] = L_init[cc];
    }
  }
  __syncthreads();

  #pragma unroll 1
  for (int k = 0; k < 4; ++k) {
    #pragma unroll 1
    for (int hc = 0; hc < 2; ++hc) {
      #pragma unroll 1
      for (int li = 0; li < 3; ++li) {
        #pragma unroll
        for (int s = 0; s < 32; ++s) zL[s] += zH[s] + cb[s];
        sublayer(zL, P1, PD1, A1h, A1l, INh, INl, rmsS, w, l);
        sublayer(zL, P2, PD2, A1h, A1l, INh, INl, rmsS, w, l);
      }
      #pragma unroll
      for (int s = 0; s < 32; ++s) zH[s] += zL[s];
      sublayer(zH, P1, PD1, A1h, A1l, INh, INl, rmsS, w, l);
      sublayer(zH, P2, PD2, A1h, A1l, INh, INl, rmsS, w, l);
    }
    // ================= k-epilogue: logits / softmax / feedback =================
    {
      float part[10];
      #pragma unroll
      for (int c = 0; c < NC; ++c) part[c] = 0.f;
      #pragma unroll
      for (int s = 0; s < 32; ++s) {
        const int r = s & 15;
        const int cc = w*64 + (s >> 4)*32 + (r & 3) + ((r >> 2) << 3) + (g << 2);
        const float zz = zH[s];
        #pragma unroll
        for (int c = 0; c < NC; ++c) part[c] += zz * W_out[cc*NC + c];
      }
      #pragma unroll
      for (int c = 0; c < NC; ++c) part[c] += __shfl_xor(part[c], 32);
      if (l < 32) {
        #pragma unroll
        for (int c = 0; c < NC; ++c) lgS[(w*32 + l)*NC + c] = part[c];
      }
      __syncthreads();
      if (w == 0 && l < 32) {
        float lg[10];
        #pragma unroll
        for (int c = 0; c < NC; ++c) lg[c] = b_out[c];
        #pragma unroll
        for (int wv = 0; wv < 8; ++wv) {
          #pragma unroll
          for (int c = 0; c < NC; ++c) lg[c] += lgS[(wv*32 + l)*NC + c];
        }
        const int row = row0 + l;
        #pragma unroll
        for (int c = 0; c < NC; ++c) out[(size_t)(1 + k)*81920 + row*NC + c] = lg[c];
        if (k == 3) {
          #pragma unroll
          for (int c = 0; c < NC; ++c) out[row*NC + c] = lg[c];
        }
        float mx = lg[0];
        #pragma unroll
        for (int c = 1; c < NC; ++c) mx = fmaxf(mx, lg[c]);
        float e[10], sum = 0.f;
        #pragma unroll
        for (int c = 0; c < NC; ++c) { e[c] = __expf(lg[c] - mx); sum += e[c]; }
        const float inv = 1.0f / sum;
        #pragma unroll
        for (int c = 0; c < NC; ++c) pbS[l*NC + c] = e[c] * inv;
      }
      __syncthreads();
      if (k < 3) {
        #pragma unroll
        for (int s = 0; s < 32; ++s) {
          const int r = s & 15;
          const int cc = w*64 + (s >> 4)*32 + (r & 3) + ((r >> 2) << 3) + (g << 2);
          float fb = b_fb[cc];
          #pragma unroll
          for (int c = 0; c < NC; ++c) fb += pbS[m*NC + c] * W_fb[c*HD + cc];
          cb[s] = xp[(size_t)(wg*8 + w)*2048 + s*64 + l] + fb;
        }
      }
      __syncthreads();   // protect lgS/pbS (A1 alias) before next A1 staging
    }
  }
}

// ===================== weight preprocessing (packed layouts) =====================
__global__ void prep_gu(const float* __restrict__ Wgu, short* __restrict__ P)
{
  const int t = blockIdx.x*256 + threadIdx.x;
  if (t >= KT1*NP*64) return;
  const int l = t & 63;
  const int rest = t >> 6;
  const int nt = rest % NP;
  const int kt = rest / NP;
  const int n  = nt*32 + (l & 31);
  const int kb = kt*16 + (l >> 5)*8;
  short8 gh8, gl8, uh8, ul8;
  #pragma unroll
  for (int i = 0; i < 8; ++i) {
    float gv = 0.f, uv = 0.f;
    if (n < 682) {
      gv = Wgu[(size_t)(kb + i)*1364 + n];
      uv = Wgu[(size_t)(kb + i)*1364 + 682 + n];
    }
    short gh = f2bf(gv); gh8[i] = gh; gl8[i] = f2bf(gv - bf2f(gh));
    short uh = f2bf(uv); uh8[i] = uh; ul8[i] = f2bf(uv - bf2f(uh));
  }
  short* dst = P + ((size_t)(kt*NP + nt)*64 + l)*32;
  *(short8*)(dst)      = gh8;
  *(short8*)(dst + 8)  = gl8;
  *(short8*)(dst + 16) = uh8;
  *(short8*)(dst + 24) = ul8;
}

__global__ void prep_d(const float* __restrict__ Wd, short* __restrict__ P)
{
  const int t = blockIdx.x*256 + threadIdx.x;
  if (t >= KT2*NTH*64) return;
  const int l = t & 63;
  const int rest = t >> 6;
  const int nt = rest % NTH;
  const int kt2 = rest / NTH;
  const int n  = nt*32 + (l & 31);
  const int kb = kt2*16 + (l >> 5)*8;
  short8 h8, l8;
  #pragma unroll
  for (int i = 0; i < 8; ++i) {
    const int k2 = kb + i;
    float v = (k2 < 682) ? Wd[(size_t)k2*HD + n] : 0.f;
    short h = f2bf(v); h8[i] = h; l8[i] = f2bf(v - bf2f(h));
  }
  short* dst = P + ((size_t)(kt2*NTH + nt)*64 + l)*16;
  *(short8*)(dst)     = h8;
  *(short8*)(dst + 8) = l8;
}

__global__ void prep_in(const float* __restrict__ Win, short* __restrict__ P)
{
  const int t = blockIdx.x*256 + threadIdx.x;
  if (t >= KTX*NTH*64) return;
  const int l = t & 63;
  const int rest = t >> 6;
  const int nt = rest % NTH;
  const int kt = rest / NTH;
  const int n  = nt*32 + (l & 31);
  const int kb = kt*16 + (l >> 5)*8;
  short8 h8, l8;
  #pragma unroll
  for (int i = 0; i < 8; ++i) {
    float v = Win[(size_t)(kb + i)*HD + n];
    short h = f2bf(v); h8[i] = h; l8[i] = f2bf(v - bf2f(h));
  }
  short* dst = P + ((size_t)(kt*NTH + nt)*64 + l)*16;
  *(short8*)(dst)     = h8;
  *(short8*)(dst + 8) = l8;
}

extern "C" void kernel_launch(void* const* d_in, const int* in_sizes, int n_in,
                              void* d_out, int out_size, void* d_ws, size_t ws_size,
                              hipStream_t stream)
{
  const float* x     = (const float*)d_in[0];
  const float* W_in  = (const float*)d_in[1];
  const float* b_in  = (const float*)d_in[2];
  const float* W_fb  = (const float*)d_in[3];
  const float* b_fb  = (const float*)d_in[4];
  const float* Wgu1  = (const float*)d_in[5];
  const float* Wd1   = (const float*)d_in[6];
  const float* Wgu2  = (const float*)d_in[7];
  const float* Wd2   = (const float*)d_in[8];
  const float* Hini  = (const float*)d_in[9];
  const float* Lini  = (const float*)d_in[10];
  const float* W_out = (const float*)d_in[11];
  const float* b_out = (const float*)d_in[12];
  float* out = (float*)d_out;

  char* ws = (char*)d_ws;
  size_t off = 0;
  auto alloc = [&](size_t bytes) {
    char* p = ws + off;
    off = (off + bytes + 255) & ~(size_t)255;
    return p;
  };
  float* xp  = (float*)alloc((size_t)NROW*HD*4);
  short* PIN = (short*)alloc((size_t)SZ_PIN*2);
  short* P1  = (short*)alloc((size_t)SZ_P1*2);
  short* PD1 = (short*)alloc((size_t)SZ_PD*2);
  short* P2  = (short*)alloc((size_t)SZ_P1*2);
  short* PD2 = (short*)alloc((size_t)SZ_PD*2);

  const int n1 = KT1*NP*64;
  prep_gu<<<(n1+255)/256, 256, 0, stream>>>(Wgu1, P1);
  prep_gu<<<(n1+255)/256, 256, 0, stream>>>(Wgu2, P2);
  const int n2 = KT2*NTH*64;
  prep_d<<<(n2+255)/256, 256, 0, stream>>>(Wd1, PD1);
  prep_d<<<(n2+255)/256, 256, 0, stream>>>(Wd2, PD2);
  const int n3 = KTX*NTH*64;
  prep_in<<<(n3+255)/256, 256, 0, stream>>>(W_in, PIN);

  trm_main<<<256, 512, 0, stream>>>(x, b_in, W_fb, b_fb, Hini, Lini, W_out, b_out,
      xp, PIN, P1, PD1, P2, PD2, out);
}

// Round 6
// 4936.660 us; speedup vs baseline: 1.0459x; 1.0459x over previous
//
#include <hip/hip_runtime.h>

#define DEVI __device__ __forceinline__

typedef __attribute__((ext_vector_type(8)))  short short8;
typedef __attribute__((ext_vector_type(4)))  short short4v;
typedef __attribute__((ext_vector_type(16))) float f32x16;

// ---- problem dims ----
constexpr int NROW = 8192;
constexpr int HD   = 512;
constexpr int DIN  = 256;
constexpr int NC   = 10;

// ---- tiling ----
constexpr int NP  = 22;   // gate/up pair tiles: 682 padded to 704 = 22*32
constexpr int KT1 = 32;   // GEMM1 K = 512 / 16
constexpr int KT2 = 44;   // GEMM2 K = 704 / 16
constexpr int KTX = 16;   // x_proj K = 256 / 16
constexpr int NTH = 16;   // H-wide outputs: 512 / 32

// packed strides (shorts per kt-step)
constexpr int KSTEP1 = NP*64*32;   // GEMM1: [gh8,gl8,uh8,ul8] per lane per (kt,nt)
constexpr int KSTEPD = NTH*64*16;  // GEMM2 / x_proj: [h8,l8]

// packed weight tensor sizes (shorts), padded +4 kt-steps for branch-free ring prefetch
constexpr int SZ_P1  = (KT1+4)*KSTEP1;
constexpr int SZ_PD  = (KT2+4)*KSTEPD;
constexpr int SZ_PIN = (KTX+4)*KSTEPD;

DEVI short f2bf(float x){
  unsigned u = __builtin_bit_cast(unsigned, x);
  unsigned r = u + 0x7FFFu + ((u >> 16) & 1u);
  return (short)(r >> 16);
}
DEVI float bf2f(short s){
  unsigned u = ((unsigned)(unsigned short)s) << 16;
  return __builtin_bit_cast(float, u);
}
DEVI f32x16 MF(short8 a, short8 b, f32x16 c){
  return __builtin_amdgcn_mfma_f32_32x32x16_bf16(a, b, c, 0, 0, 0);
}
DEVI f32x16 fzero(){
  f32x16 v;
  #pragma unroll
  for (int i = 0; i < 16; ++i) v[i] = 0.f;
  return v;
}

// store silu(gate)*up for one 32-col pair into inter frag buffers (hi/lo bf16)
DEVI void silu_store(int p, const f32x16& cg, const f32x16& cu,
                     short* INh_, short* INl_, int l)
{
  const int m = l & 31, g = l >> 5;
  #pragma unroll
  for (int q = 0; q < 4; ++q) {
    short4v hi, lo;
    #pragma unroll
    for (int pos = 0; pos < 4; ++pos) {
      const int r = q*4 + pos;
      float gv = cg[r], uv = cu[r];
      float sv = (gv / (1.0f + __expf(-gv))) * uv;   // silu(g)*u
      short h = f2bf(sv);
      hi[pos] = h;
      lo[pos] = f2bf(sv - bf2f(h));
    }
    const int kt2  = 2*p + (q >> 1);
    const int slot = ((q & 1) << 5) + m;
    const int base = (kt2*64 + slot)*8 + (g << 2);
    *(short4v*)&INh_[base] = hi;
    *(short4v*)&INl_[base] = lo;
  }
}

// GEMM1, ONE (gate,up) pair, depth-2 register ring pipeline (static indices only).
// bW = P + ((pair*64 + l))*32. Requires >=2 kt-steps of tail padding in P.
DEVI void g1_pair(const short* __restrict__ bW,
                  const short* __restrict__ A1h_, const short* __restrict__ A1l_,
                  int l, f32x16& ag, f32x16& au)
{
  short8 R0[4], R1[4];   // ring slots: {gh,gl,uh,ul}
  auto LD = [&](short8* R, int kt) {
    const short* p = bW + (size_t)kt*KSTEP1;
    R[0] = *(const short8*)(p);
    R[1] = *(const short8*)(p + 8);
    R[2] = *(const short8*)(p + 16);
    R[3] = *(const short8*)(p + 24);
  };
  LD(R0, 0); LD(R1, 1);
  #pragma unroll 1
  for (int kt = 0; kt < KT1; kt += 2) {
    #define G1STEP(R, u) { \
      short8 bh = *(const short8*)&A1h_[((kt+u)*64 + l)*8]; \
      short8 bl = *(const short8*)&A1l_[((kt+u)*64 + l)*8]; \
      ag = MF(R[0], bh, ag); ag = MF(R[1], bh, ag); ag = MF(R[0], bl, ag); \
      au = MF(R[2], bh, au); au = MF(R[3], bh, au); au = MF(R[2], bl, au); \
      LD(R, kt + u + 2); }
    G1STEP(R0, 0) G1STEP(R1, 1)
    #undef G1STEP
  }
}

// GEMM2 / x_proj: two output cols, depth-2 register ring pipeline.
// bD = P + ((2w*64 + l))*16. Requires >=2 kt-steps of tail padding in P.
template<int KT>
DEVI void g2_run(const short* __restrict__ bD,
                 const short* __restrict__ Bh_, const short* __restrict__ Bl_,
                 int l, f32x16& c0, f32x16& c1)
{
  short8 R0[4], R1[4];   // ring slots: {d0h,d0l,d1h,d1l}
  auto LD = [&](short8* R, int kt) {
    const short* p = bD + (size_t)kt*KSTEPD;
    R[0] = *(const short8*)(p);
    R[1] = *(const short8*)(p + 8);
    R[2] = *(const short8*)(p + 1024);
    R[3] = *(const short8*)(p + 1032);
  };
  LD(R0, 0); LD(R1, 1);
  #pragma unroll 1
  for (int kt = 0; kt < KT; kt += 2) {
    #define G2STEP(R, u) { \
      short8 bh = *(const short8*)&Bh_[((kt+u)*64 + l)*8]; \
      short8 bl = *(const short8*)&Bl_[((kt+u)*64 + l)*8]; \
      c0 = MF(R[0], bh, c0); c0 = MF(R[1], bh, c0); c0 = MF(R[0], bl, c0); \
      c1 = MF(R[2], bh, c1); c1 = MF(R[3], bh, c1); c1 = MF(R[2], bl, c1); \
      LD(R, kt + u + 2); }
    G2STEP(R0, 0) G2STEP(R1, 1)
    #undef G2STEP
  }
}

// one SwiGLU sublayer + residual + rmsnorm, in-place on register state S[32]
DEVI void sublayer(float (&S)[32], const short* __restrict__ PW, const short* __restrict__ PD,
                   short* A1h_, short* A1l_, short* INh_, short* INl_,
                   float* rmsS_, int w, int l)
{
  const int m = l & 31, g = l >> 5;
  // ---- stage h0 fragments (hi/lo) into LDS ----
  #pragma unroll
  for (int t = 0; t < 2; ++t) {
    #pragma unroll
    for (int q = 0; q < 4; ++q) {
      short4v hi, lo;
      #pragma unroll
      for (int pos = 0; pos < 4; ++pos) {
        float v = S[t*16 + q*4 + pos];
        short h = f2bf(v);
        hi[pos] = h;
        lo[pos] = f2bf(v - bf2f(h));
      }
      const int kt   = 4*w + 2*t + (q >> 1);
      const int slot = ((q & 1) << 5) + m;
      const int base = (kt*64 + slot)*8 + (g << 2);
      *(short4v*)&A1h_[base] = hi;
      *(short4v*)&A1l_[base] = lo;
    }
  }
  __syncthreads();
  // ---- GEMM1 (weights are MFMA A-operand), one pair per pass ----
  {
    f32x16 ag = fzero(), au = fzero();
    g1_pair(PW + ((size_t)(w*64 + l))*32, A1h_, A1l_, l, ag, au);
    silu_store(w, ag, au, INh_, INl_, l);
  }
  {
    f32x16 ag = fzero(), au = fzero();
    g1_pair(PW + ((size_t)((w + 8)*64 + l))*32, A1h_, A1l_, l, ag, au);
    silu_store(w + 8, ag, au, INh_, INl_, l);
  }
  if (w < 6) {
    f32x16 ag = fzero(), au = fzero();
    g1_pair(PW + ((size_t)((w + 16)*64 + l))*32, A1h_, A1l_, l, ag, au);
    silu_store(w + 16, ag, au, INh_, INl_, l);
  }
  __syncthreads();
  // ---- GEMM2 ----
  f32x16 c0 = fzero(), c1 = fzero();
  g2_run<KT2>(PD + ((size_t)(2*w*64 + l))*16, INh_, INl_, l, c0, c1);
  // ---- residual + rmsnorm (thread-local: C^T frags align with state) ----
  float ss = 0.f;
  #pragma unroll
  for (int s = 0; s < 32; ++s) {
    float y = S[s] + (s < 16 ? c0[s & 15] : c1[s & 15]);
    S[s] = y;
    ss += y*y;
  }
  ss += __shfl_xor(ss, 32);
  if (l < 32) rmsS_[w*32 + l] = ss;
  __syncthreads();
  float tot = 0.f;
  #pragma unroll
  for (int wv = 0; wv < 8; ++wv) tot += rmsS_[wv*32 + m];
  const float rinv = 1.0f / sqrtf(tot * (1.0f/512.0f) + 1e-6f);
  #pragma unroll
  for (int s = 0; s < 32; ++s) S[s] *= rinv;
}

__global__
__attribute__((amdgpu_flat_work_group_size(512, 512)))
__attribute__((amdgpu_waves_per_eu(2, 2)))
void trm_main(
    const float* __restrict__ x,
    const float* __restrict__ b_in,
    const float* __restrict__ W_fb,
    const float* __restrict__ b_fb,
    const float* __restrict__ H_init,
    const float* __restrict__ L_init,
    const float* __restrict__ W_out,
    const float* __restrict__ b_out,
    float* __restrict__ xp,
    const short* __restrict__ PIN,
    const short* __restrict__ P1, const short* __restrict__ PD1,
    const short* __restrict__ P2, const short* __restrict__ PD2,
    float* __restrict__ out)
{
  __shared__ alignas(16) char smem[156672];
  short* A1h  = (short*)(smem);            // [32][64][8] bf16-hi h0 frags (32KB)
  short* A1l  = (short*)(smem + 32768);    // lo (32KB)
  short* INh  = (short*)(smem + 65536);    // [44][64][8] inter hi (45KB)
  short* INl  = (short*)(smem + 110592);   // lo (45KB)
  float* rmsS = (float*)(smem + 155648);   // [8][32]
  float* lgS  = (float*)(smem);            // k-epilogue alias over A1 region
  float* pbS  = (float*)(smem + 10240);

  const int tid = threadIdx.x;
  const int l = tid & 63;
  const int w = tid >> 6;
  const int m = l & 31;
  const int g = l >> 5;
  const int wg = blockIdx.x;
  const int row0 = wg * 32;

  float zL[32], zH[32], cb[32];

  // ================= x_proj = x @ W_in + b_in =================
  #pragma unroll
  for (int kk = 0; kk < 2; ++kk) {
    const int kt = 2*w + kk;
    const float4* xr = (const float4*)(x + (size_t)(row0 + m)*DIN + kt*16 + g*8);
    float4 v0 = xr[0];
    float4 v1 = xr[1];
    float v[8] = {v0.x, v0.y, v0.z, v0.w, v1.x, v1.y, v1.z, v1.w};
    short8 hi, lo;
    #pragma unroll
    for (int i = 0; i < 8; ++i) {
      short h = f2bf(v[i]);
      hi[i] = h;
      lo[i] = f2bf(v[i] - bf2f(h));
    }
    const int base = (kt*64 + l)*8;
    *(short8*)&A1h[base] = hi;
    *(short8*)&A1l[base] = lo;
  }
  __syncthreads();
  {
    f32x16 c0 = fzero(), c1 = fzero();
    g2_run<KTX>(PIN + ((size_t)(2*w*64 + l))*16, A1h, A1l, l, c0, c1);
    #pragma unroll
    for (int s = 0; s < 32; ++s) {
      const int r = s & 15;
      const int cc = w*64 + (s >> 4)*32 + (r & 3) + ((r >> 2) << 3) + (g << 2);
      float v = (s < 16 ? c0[r] : c1[r]) + b_in[cc];
      cb[s] = v;
      xp[(size_t)(wg*8 + w)*2048 + s*64 + l] = v;
      zH[s] = H_init[cc];
      zL[s] = L_init[cc];
    }
  }
  __syncthreads();

  #pragma unroll 1
  for (int k = 0; k < 4; ++k) {
    #pragma unroll 1
    for (int hc = 0; hc < 2; ++hc) {
      #pragma unroll 1
      for (int li = 0; li < 3; ++li) {
        #pragma unroll
        for (int s = 0; s < 32; ++s) zL[s] += zH[s] + cb[s];
        sublayer(zL, P1, PD1, A1h, A1l, INh, INl, rmsS, w, l);
        sublayer(zL, P2, PD2, A1h, A1l, INh, INl, rmsS, w, l);
      }
      #pragma unroll
      for (int s = 0; s < 32; ++s) zH[s] += zL[s];
      sublayer(zH, P1, PD1, A1h, A1l, INh, INl, rmsS, w, l);
      sublayer(zH, P2, PD2, A1h, A1l, INh, INl, rmsS, w, l);
    }
    // ================= k-epilogue: logits / softmax / feedback =================
    {
      float part[10];
      #pragma unroll
      for (int c = 0; c < NC; ++c) part[c] = 0.f;
      #pragma unroll
      for (int s = 0; s < 32; ++s) {
        const int r = s & 15;
        const int cc = w*64 + (s >> 4)*32 + (r & 3) + ((r >> 2) << 3) + (g << 2);
        const float zz = zH[s];
        #pragma unroll
        for (int c = 0; c < NC; ++c) part[c] += zz * W_out[cc*NC + c];
      }
      #pragma unroll
      for (int c = 0; c < NC; ++c) part[c] += __shfl_xor(part[c], 32);
      if (l < 32) {
        #pragma unroll
        for (int c = 0; c < NC; ++c) lgS[(w*32 + l)*NC + c] = part[c];
      }
      __syncthreads();
      if (w == 0 && l < 32) {
        float lg[10];
        #pragma unroll
        for (int c = 0; c < NC; ++c) lg[c] = b_out[c];
        #pragma unroll
        for (int wv = 0; wv < 8; ++wv) {
          #pragma unroll
          for (int c = 0; c < NC; ++c) lg[c] += lgS[(wv*32 + l)*NC + c];
        }
        const int row = row0 + l;
        #pragma unroll
        for (int c = 0; c < NC; ++c) out[(size_t)(1 + k)*81920 + row*NC + c] = lg[c];
        if (k == 3) {
          #pragma unroll
          for (int c = 0; c < NC; ++c) out[row*NC + c] = lg[c];
        }
        float mx = lg[0];
        #pragma unroll
        for (int c = 1; c < NC; ++c) mx = fmaxf(mx, lg[c]);
        float e[10], sum = 0.f;
        #pragma unroll
        for (int c = 0; c < NC; ++c) { e[c] = __expf(lg[c] - mx); sum += e[c]; }
        const float inv = 1.0f / sum;
        #pragma unroll
        for (int c = 0; c < NC; ++c) pbS[l*NC + c] = e[c] * inv;
      }
      __syncthreads();
      if (k < 3) {
        #pragma unroll
        for (int s = 0; s < 32; ++s) {
          const int r = s & 15;
          const int cc = w*64 + (s >> 4)*32 + (r & 3) + ((r >> 2) << 3) + (g << 2);
          float fb = b_fb[cc];
          #pragma unroll
          for (int c = 0; c < NC; ++c) fb += pbS[m*NC + c] * W_fb[c*HD + cc];
          cb[s] = xp[(size_t)(wg*8 + w)*2048 + s*64 + l] + fb;
        }
      }
      __syncthreads();   // protect lgS/pbS (A1 alias) before next A1 staging
    }
  }
}

// ===================== weight preprocessing (packed layouts) =====================
__global__ void prep_gu(const float* __restrict__ Wgu, short* __restrict__ P)
{
  const int t = blockIdx.x*256 + threadIdx.x;
  if (t >= KT1*NP*64) return;
  const int l = t & 63;
  const int rest = t >> 6;
  const int nt = rest % NP;
  const int kt = rest / NP;
  const int n  = nt*32 + (l & 31);
  const int kb = kt*16 + (l >> 5)*8;
  short8 gh8, gl8, uh8, ul8;
  #pragma unroll
  for (int i = 0; i < 8; ++i) {
    float gv = 0.f, uv = 0.f;
    if (n < 682) {
      gv = Wgu[(size_t)(kb + i)*1364 + n];
      uv = Wgu[(size_t)(kb + i)*1364 + 682 + n];
    }
    short gh = f2bf(gv); gh8[i] = gh; gl8[i] = f2bf(gv - bf2f(gh));
    short uh = f2bf(uv); uh8[i] = uh; ul8[i] = f2bf(uv - bf2f(uh));
  }
  short* dst = P + ((size_t)(kt*NP + nt)*64 + l)*32;
  *(short8*)(dst)      = gh8;
  *(short8*)(dst + 8)  = gl8;
  *(short8*)(dst + 16) = uh8;
  *(short8*)(dst + 24) = ul8;
}

__global__ void prep_d(const float* __restrict__ Wd, short* __restrict__ P)
{
  const int t = blockIdx.x*256 + threadIdx.x;
  if (t >= KT2*NTH*64) return;
  const int l = t & 63;
  const int rest = t >> 6;
  const int nt = rest % NTH;
  const int kt2 = rest / NTH;
  const int n  = nt*32 + (l & 31);
  const int kb = kt2*16 + (l >> 5)*8;
  short8 h8, l8;
  #pragma unroll
  for (int i = 0; i < 8; ++i) {
    const int k2 = kb + i;
    float v = (k2 < 682) ? Wd[(size_t)k2*HD + n] : 0.f;
    short h = f2bf(v); h8[i] = h; l8[i] = f2bf(v - bf2f(h));
  }
  short* dst = P + ((size_t)(kt2*NTH + nt)*64 + l)*16;
  *(short8*)(dst)     = h8;
  *(short8*)(dst + 8) = l8;
}

__global__ void prep_in(const float* __restrict__ Win, short* __restrict__ P)
{
  const int t = blockIdx.x*256 + threadIdx.x;
  if (t >= KTX*NTH*64) return;
  const int l = t & 63;
  const int rest = t >> 6;
  const int nt = rest % NTH;
  const int kt = rest / NTH;
  const int n  = nt*32 + (l & 31);
  const int kb = kt*16 + (l >> 5)*8;
  short8 h8, l8;
  #pragma unroll
  for (int i = 0; i < 8; ++i) {
    float v = Win[(size_t)(kb + i)*HD + n];
    short h = f2bf(v); h8[i] = h; l8[i] = f2bf(v - bf2f(h));
  }
  short* dst = P + ((size_t)(kt*NTH + nt)*64 + l)*16;
  *(short8*)(dst)     = h8;
  *(short8*)(dst + 8) = l8;
}

extern "C" void kernel_launch(void* const* d_in, const int* in_sizes, int n_in,
                              void* d_out, int out_size, void* d_ws, size_t ws_size,
                              hipStream_t stream)
{
  const float* x     = (const float*)d_in[0];
  const float* W_in  = (const float*)d_in[1];
  const float* b_in  = (const float*)d_in[2];
  const float* W_fb  = (const float*)d_in[3];
  const float* b_fb  = (const float*)d_in[4];
  const float* Wgu1  = (const float*)d_in[5];
  const float* Wd1   = (const float*)d_in[6];
  const float* Wgu2  = (const float*)d_in[7];
  const float* Wd2   = (const float*)d_in[8];
  const float* Hini  = (const float*)d_in[9];
  const float* Lini  = (const float*)d_in[10];
  const float* W_out = (const float*)d_in[11];
  const float* b_out = (const float*)d_in[12];
  float* out = (float*)d_out;

  char* ws = (char*)d_ws;
  size_t off = 0;
  auto alloc = [&](size_t bytes) {
    char* p = ws + off;
    off = (off + bytes + 255) & ~(size_t)255;
    return p;
  };
  float* xp  = (float*)alloc((size_t)NROW*HD*4);
  short* PIN = (short*)alloc((size_t)SZ_PIN*2);
  short* P1  = (short*)alloc((size_t)SZ_P1*2);
  short* PD1 = (short*)alloc((size_t)SZ_PD*2);
  short* P2  = (short*)alloc((size_t)SZ_P1*2);
  short* PD2 = (short*)alloc((size_t)SZ_PD*2);

  const int n1 = KT1*NP*64;
  prep_gu<<<(n1+255)/256, 256, 0, stream>>>(Wgu1, P1);
  prep_gu<<<(n1+255)/256, 256, 0, stream>>>(Wgu2, P2);
  const int n2 = KT2*NTH*64;
  prep_d<<<(n2+255)/256, 256, 0, stream>>>(Wd1, PD1);
  prep_d<<<(n2+255)/256, 256, 0, stream>>>(Wd2, PD2);
  const int n3 = KTX*NTH*64;
  prep_in<<<(n3+255)/256, 256, 0, stream>>>(W_in, PIN);

  trm_main<<<256, 512, 0, stream>>>(x, b_in, W_fb, b_fb, Hini, Lini, W_out, b_out,
      xp, PIN, P1, PD1, P2, PD2, out);
}